// Round 4
// baseline (992.315 us; speedup 1.0000x reference)
//
#include <hip/hip_runtime.h>
#include <cstdint>
#include <cstddef>

#define DEVI __device__ __forceinline__

typedef __attribute__((ext_vector_type(8))) short short8;
typedef __attribute__((ext_vector_type(4))) float f32x4;
typedef __bf16 bf16x8 __attribute__((ext_vector_type(8)));

DEVI float sigf(float x) { return 1.0f / (1.0f + __expf(-x)); }
DEVI float tanh_f(float x) { return 2.0f / (1.0f + __expf(-2.0f * x)) - 1.0f; }

DEVI short f2bf(float x) {
    uint32_t u = __builtin_bit_cast(uint32_t, x);
    u += 0x7FFFu + ((u >> 16) & 1u);   // RTNE
    return (short)(u >> 16);
}
DEVI float bf2f(short s) {
    uint32_t u = ((uint32_t)(unsigned short)s) << 16;
    return __builtin_bit_cast(float, u);
}

DEVI void gload16(const void* g, void* l) {
    __builtin_amdgcn_global_load_lds(
        (const __attribute__((address_space(1))) void*)g,
        (__attribute__((address_space(3))) void*)l, 16, 0, 0);
}

DEVI f32x4 mfma16(short8 a, short8 b, f32x4 c) {
    return __builtin_amdgcn_mfma_f32_16x16x32_bf16(
        __builtin_bit_cast(bf16x8, a), __builtin_bit_cast(bf16x8, b), c, 0, 0, 0);
}

// ---------------- prep kernels ----------------

// Wstk[n'][k], n' = hblk*64 + gate*16 + hl  (orig gate row = gate*1024 + hblk*16 + hl)
// k: [0,300)=W_ih, k==300 -> b_ih+b_hh (paired with constant-1.0 x column),
//    (300,320)=0, [320,1344)=W_hh
__global__ __launch_bounds__(256) void prep_wstk(const float* __restrict__ Wih,
                                                 const float* __restrict__ Whh,
                                                 const float* __restrict__ bih,
                                                 const float* __restrict__ bhh,
                                                 short* __restrict__ Wstk) {
    int idx = blockIdx.x * 256 + threadIdx.x;
    if (idx >= 4096 * 1344) return;
    int n = idx / 1344, k = idx - n * 1344;
    int hblk = n >> 6, gate = (n >> 4) & 3, hl = n & 15;
    int on = gate * 1024 + hblk * 16 + hl;
    float v = 0.f;
    if (k < 300) v = Wih[on * 300 + k];
    else if (k == 300) v = bih[on] + bhh[on];
    else if (k >= 320) v = Whh[on * 1024 + (k - 320)];
    Wstk[idx] = f2bf(v);
}

// x_bf16[t][b][e], e in [0,320): e<300 -> q, e==300 -> 1.0 (bias), else 0.
__global__ __launch_bounds__(256) void prep_x(const float* __restrict__ q,
                                              short* __restrict__ xb) {
    int idx = blockIdx.x * 256 + threadIdx.x;
    if (idx >= 14 * 256 * 320) return;
    int t = idx / (256 * 320);
    int r = idx - t * 256 * 320;
    int b = r / 320, e = r - b * 320;
    float v = (e < 300) ? q[(b * 14 + t) * 300 + e] : (e == 300 ? 1.0f : 0.0f);
    xb[idx] = f2bf(v);
}

// Wcat[n'][k], n' in [0,1024): hg=n'>>5, which=(n'>>4)&1, h=hg*16+(n'&15).
__global__ __launch_bounds__(256) void prep_wcat(const float* __restrict__ Ww,
                                                 const float* __restrict__ Wpw,
                                                 short* __restrict__ Wcat) {
    int idx = blockIdx.x * 256 + threadIdx.x;
    if (idx >= 1024 * 3072) return;
    int n = idx / 3072, k = idx - n * 3072;
    int hg = n >> 5, which = (n >> 4) & 1, hl = n & 15;
    int h = hg * 16 + hl;
    const float* src = which ? Wpw : Ww;
    Wcat[idx] = f2bf(src[h * 3072 + k]);
}

// exclusive prefix sum of index[256] -> cum[0..256], cum[256] = Mlive
__global__ __launch_bounds__(256) void prep_index(const int* __restrict__ index,
                                                  int* __restrict__ cum) {
    __shared__ int s[256];
    int t = threadIdx.x;
    s[t] = index[t];
    __syncthreads();
    for (int off = 1; off < 256; off <<= 1) {
        int v = (t >= off) ? s[t - off] : 0;
        __syncthreads();
        s[t] += v;
        __syncthreads();
    }
    cum[t + 1] = s[t];
    if (t == 0) cum[0] = 0;
}

// Compact live rows into Ac[dr][3072] bf16: cols [0,2048) = box row (f32->bf16),
// cols [2048,3072) = h[b]. dr = cum[b] + j. One block per original row.
__global__ __launch_bounds__(256) void compact_a(const float* __restrict__ box,
                                                 const short* __restrict__ hb,
                                                 const int* __restrict__ index,
                                                 const int* __restrict__ cum,
                                                 short* __restrict__ Ac) {
    int m = blockIdx.x;                  // 25600
    int b = m / 100, j = m - b * 100;
    if (j >= index[b]) return;
    size_t dr = (size_t)(cum[b] + j);
    int t = threadIdx.x;
    const float* src = box + (size_t)m * 2048 + t * 8;
    float4 v0 = *(const float4*)src;
    float4 v1 = *(const float4*)(src + 4);
    short8 s;
    s[0] = f2bf(v0.x); s[1] = f2bf(v0.y); s[2] = f2bf(v0.z); s[3] = f2bf(v0.w);
    s[4] = f2bf(v1.x); s[5] = f2bf(v1.y); s[6] = f2bf(v1.z); s[7] = f2bf(v1.w);
    *(short8*)&Ac[dr * 3072 + t * 8] = s;
    if (t < 128)
        *(short8*)&Ac[dr * 3072 + 2048 + t * 8] = *(const short8*)&hb[b * 1024 + t * 8];
}

// ---------------- LSTM part 1: x-projection for all timesteps ----------------

// xg[t*256+b][n'] = xb @ Wstk(:, 0:320)^T, bf16 out. M=3584, N=4096, K=320.
__global__ __launch_bounds__(256) void xg_gemm(const short* __restrict__ xb,   // [3584][320]
                                               const short* __restrict__ Wstk, // [4096][1344]
                                               short* __restrict__ xg) {       // [3584][4096]
    __shared__ __attribute__((aligned(16))) short As[128 * 64];
    __shared__ __attribute__((aligned(16))) short Bs[128 * 64];
    const int tid = threadIdx.x, l = tid & 63, w = tid >> 6;
    const int n0 = blockIdx.x * 128;  // 32
    const int m0 = blockIdx.y * 128;  // 28
    const int wm = w >> 1, wn = w & 1;

    const short* asrc[4];
    const short* bsrc[4];
    for (int i = 0; i < 4; i++) {
        int r = w * 32 + i * 8 + (l >> 3);
        int cs = (l & 7) ^ (r & 7);
        asrc[i] = xb + (size_t)(m0 + r) * 320 + cs * 8;
        bsrc[i] = Wstk + (size_t)(n0 + r) * 1344 + cs * 8;
    }

    f32x4 acc[4][4];
    for (int i = 0; i < 4; i++)
        for (int j = 0; j < 4; j++) acc[i][j] = f32x4{0.f, 0.f, 0.f, 0.f};

    for (int kt = 0; kt < 5; ++kt) {
        const int k0 = kt * 64;
        __syncthreads();
        for (int i = 0; i < 4; i++)
            gload16(asrc[i] + k0, &As[(w * 32 + i * 8) * 64]);
        for (int i = 0; i < 4; i++)
            gload16(bsrc[i] + k0, &Bs[(w * 32 + i * 8) * 64]);
        __syncthreads();
        for (int ks = 0; ks < 2; ++ks) {
            short8 a[4], b[4];
            for (int mf = 0; mf < 4; ++mf) {
                int m = wm * 64 + mf * 16 + (l & 15);
                int ca = (ks * 4 + (l >> 4)) ^ (m & 7);
                a[mf] = *(const short8*)&As[m * 64 + ca * 8];
            }
            for (int nf = 0; nf < 4; ++nf) {
                int n = wn * 64 + nf * 16 + (l & 15);
                int cb = (ks * 4 + (l >> 4)) ^ (n & 7);
                b[nf] = *(const short8*)&Bs[n * 64 + cb * 8];
            }
            for (int mf = 0; mf < 4; ++mf)
                for (int nf = 0; nf < 4; ++nf)
                    acc[mf][nf] = mfma16(a[mf], b[nf], acc[mf][nf]);
        }
    }
    const int hl = l & 15, hi = l >> 4;
    for (int mf = 0; mf < 4; ++mf)
        for (int nf = 0; nf < 4; ++nf)
            for (int rg = 0; rg < 4; ++rg) {
                int row = m0 + wm * 64 + mf * 16 + hi * 4 + rg;
                int col = n0 + wn * 64 + nf * 16 + hl;
                xg[(size_t)row * 4096 + col] = f2bf(acc[mf][nf][rg]);
            }
}

// ---------------- LSTM part 2: persistent recurrence ----------------

// grid = 256 blocks (1/CU, forced by 147KB LDS), block = (mx = bid>>6, ny = bid&63).
// W_hh slice (64 n' x 1024 k) LDS-resident across all steps; c in registers.
// Per-step sync: device-scope atomic group barrier over the 64 blocks of one mx.
__global__ __launch_bounds__(256, 1) void lstm_persist(
        const short* __restrict__ xg,    // [3584][4096] bf16
        const short* __restrict__ Wstk,  // [4096][1344]
        short* __restrict__ hb0,         // h buffers, ping-pong; final h_14 in hb0
        short* __restrict__ hb1,
        int* __restrict__ ctr) {         // [14*16] zeroed
    __shared__ __attribute__((aligned(16))) short W_s[64 * 1024];   // 128 KB
    __shared__ __attribute__((aligned(16))) short As[2][64 * 64];   // 16 KB
    const int tid = threadIdx.x, l = tid & 63, w = tid >> 6;
    const int hi = l >> 4, hl = l & 15;
    const int bid = blockIdx.x;
    const int mx = bid >> 6, ny = bid & 63;
    const int m0 = mx * 64, n0g = ny * 64;

    // preload W_hh slice (global cols 320..1344), XOR-swizzled chunk layout
    for (int i = 0; i < 32; ++i) {
        int s = i * 256 + w * 64 + l;
        int n = s >> 7, pc = s & 127;
        const short* src = Wstk + (size_t)(n0g + n) * 1344 + 320 + ((pc ^ (n & 7)) * 8);
        gload16(src, W_s + (size_t)(i * 256 + w * 64) * 8);
    }
    __syncthreads();

    // per-thread A-staging constants (2 slots of 16B per thread per k-tile)
    const int s0 = w * 128 + l, s1 = s0 + 64;
    const int r0 = s0 >> 3, r1 = s1 >> 3;
    const int aoff0 = (m0 + r0) * 1024 + (((s0 & 7) ^ (r0 & 7)) * 8);
    const int aoff1 = (m0 + r1) * 1024 + (((s1 & 7) ^ (r1 & 7)) * 8);

    float creg[4] = {0.f, 0.f, 0.f, 0.f};

    for (int t = 0; t < 14; ++t) {
        f32x4 acc[4];
#pragma unroll
        for (int i = 0; i < 4; i++) acc[i] = f32x4{0.f, 0.f, 0.f, 0.f};

        if (t >= 1) {
            // wait: all 64 blocks of this mx finished writing h_t
            if (tid == 0) {
                int guard = 0;
                while (__hip_atomic_load(&ctr[(t - 1) * 16], __ATOMIC_RELAXED,
                                         __HIP_MEMORY_SCOPE_AGENT) < 64 &&
                       guard < (1 << 20)) {
                    __builtin_amdgcn_s_sleep(8);
                    ++guard;
                }
            }
            __syncthreads();
            __threadfence();   // acquire: invalidate caches before reading h_t

            const short* hprev = (t & 1) ? hb1 : hb0;   // h_t
            const short* ap0 = hprev + aoff0;
            const short* ap1 = hprev + aoff1;
            // prologue: stage kt=0 into buf 0
            gload16(ap0, &As[0][(size_t)w * 1024]);
            gload16(ap1, &As[0][(size_t)w * 1024 + 512]);
#pragma unroll
            for (int kt = 0; kt < 16; ++kt) {
                if (kt < 15) {
                    gload16(ap0 + (kt + 1) * 64, &As[(kt + 1) & 1][(size_t)w * 1024]);
                    gload16(ap1 + (kt + 1) * 64, &As[(kt + 1) & 1][(size_t)w * 1024 + 512]);
                    asm volatile("s_waitcnt vmcnt(2)" ::: "memory");
                } else {
                    asm volatile("s_waitcnt vmcnt(0)" ::: "memory");
                }
                __builtin_amdgcn_sched_barrier(0);
                __builtin_amdgcn_s_barrier();
                __builtin_amdgcn_sched_barrier(0);
                const short* Ab = As[kt & 1];
#pragma unroll
                for (int ks = 0; ks < 2; ++ks) {
                    const int mrow = w * 16 + hl;
                    const int ca = (ks * 4 + hi) ^ (hl & 7);
                    short8 a = *(const short8*)&Ab[mrow * 64 + ca * 8];
#pragma unroll
                    for (int nf = 0; nf < 4; ++nf) {
                        const int nrow = nf * 16 + hl;
                        const int cb = kt * 8 + ((ks * 4 + hi) ^ (hl & 7));
                        short8 b = *(const short8*)&W_s[nrow * 1024 + cb * 8];
                        acc[nf] = mfma16(a, b, acc[nf]);
                    }
                }
                __builtin_amdgcn_sched_barrier(0);
                asm volatile("s_waitcnt lgkmcnt(0)" ::: "memory");
                __builtin_amdgcn_s_barrier();
                __builtin_amdgcn_sched_barrier(0);
            }
        }

        // epilogue: gates = acc + xg[t]; cell update; write h_{t+1}
        const short* xr0 = xg + ((size_t)(t * 256 + m0 + w * 16 + hi * 4)) * 4096 + n0g + hl;
        short* hnext = ((t + 1) & 1) ? hb1 : hb0;
#pragma unroll
        for (int rg = 0; rg < 4; ++rg) {
            const short* xr = xr0 + (size_t)rg * 4096;
            float ig = acc[0][rg] + bf2f(xr[0]);
            float fg = acc[1][rg] + bf2f(xr[16]);
            float gg = acc[2][rg] + bf2f(xr[32]);
            float og = acc[3][rg] + bf2f(xr[48]);
            float cn = sigf(fg) * creg[rg] + sigf(ig) * tanh_f(gg);
            creg[rg] = cn;
            int row = m0 + w * 16 + hi * 4 + rg;
            hnext[(size_t)row * 1024 + ny * 16 + hl] = f2bf(sigf(og) * tanh_f(cn));
        }

        __threadfence();   // release h_{t+1} stores
        __syncthreads();
        if (tid == 0 && t < 13)
            __hip_atomic_fetch_add(&ctr[t * 16], 1, __ATOMIC_RELEASE,
                                   __HIP_MEMORY_SCOPE_AGENT);
    }
}

// ---------------- gated MLP (compacted, uniform, branch-free) ----------------

__global__ __launch_bounds__(256) void mlp_gemm(const short* __restrict__ Ac,   // [Mpad][3072]
                                                const short* __restrict__ Wcat, // [1024][3072]
                                                const int* __restrict__ mliveptr,
                                                const float* __restrict__ Wb,
                                                const float* __restrict__ Wpb,
                                                const float* __restrict__ fw,
                                                float* __restrict__ logits) {
    __shared__ __attribute__((aligned(16))) short As[128 * 64];
    __shared__ __attribute__((aligned(16))) short Bs[128 * 64];
    const int Mlive = *mliveptr;
    const int tid = threadIdx.x, l = tid & 63, w = tid >> 6;
    const int bid = blockIdx.x;              // 1600
    const int xcd = bid & 7, ii = bid >> 3;  // ii in [0,200)
    const int x = ii & 7, q = ii >> 3;       // q in [0,25)
    const int y = q * 8 + xcd;
    const int n0 = x * 128, m0 = y * 128;
    if (m0 >= Mlive) return;
    const int wm = w >> 1, wn = w & 1;

    const short* asrc[4];
    const short* bsrc[4];
    for (int i = 0; i < 4; i++) {
        int r = w * 32 + i * 8 + (l >> 3);
        int cs = (l & 7) ^ (r & 7);
        asrc[i] = Ac + (size_t)(m0 + r) * 3072 + cs * 8;
        bsrc[i] = Wcat + (size_t)(n0 + r) * 3072 + cs * 8;
    }

    f32x4 acc[4][4];
    for (int i = 0; i < 4; i++)
        for (int j = 0; j < 4; j++) acc[i][j] = f32x4{0.f, 0.f, 0.f, 0.f};

    for (int kt = 0; kt < 48; ++kt) {
        const int k0 = kt * 64;
        __syncthreads();
        for (int i = 0; i < 4; i++)
            gload16(asrc[i] + k0, &As[(w * 32 + i * 8) * 64]);
        for (int i = 0; i < 4; i++)
            gload16(bsrc[i] + k0, &Bs[(w * 32 + i * 8) * 64]);
        __syncthreads();
        for (int ks = 0; ks < 2; ++ks) {
            short8 a[4], b[4];
            for (int mf = 0; mf < 4; ++mf) {
                int m = wm * 64 + mf * 16 + (l & 15);
                int ca = (ks * 4 + (l >> 4)) ^ (m & 7);
                a[mf] = *(const short8*)&As[m * 64 + ca * 8];
            }
            for (int nf = 0; nf < 4; ++nf) {
                int n = wn * 64 + nf * 16 + (l & 15);
                int cb = (ks * 4 + (l >> 4)) ^ (n & 7);
                b[nf] = *(const short8*)&Bs[n * 64 + cb * 8];
            }
            for (int mf = 0; mf < 4; ++mf)
                for (int nf = 0; nf < 4; ++nf)
                    acc[mf][nf] = mfma16(a[mf], b[nf], acc[mf][nf]);
        }
    }

    const int hl = l & 15, hi = l >> 4;
    for (int mf = 0; mf < 4; ++mf) {
        float part[4] = {0.f, 0.f, 0.f, 0.f};
        for (int p = 0; p < 2; ++p) {
            int ntg = (n0 + wn * 64) / 16 + 2 * p;
            int hg = ntg >> 1;
            int h = hg * 16 + hl;
            float fwv = fw[h], wbv = Wb[h], wpbv = Wpb[h];
            for (int rg = 0; rg < 4; ++rg) {
                float y2 = tanh_f(acc[mf][2 * p][rg] + wbv);
                float g2 = sigf(acc[mf][2 * p + 1][rg] + wpbv);
                part[rg] += y2 * g2 * fwv;
            }
        }
        for (int rg = 0; rg < 4; ++rg) {
            float v = part[rg];
            v += __shfl_xor(v, 1, 64);
            v += __shfl_xor(v, 2, 64);
            v += __shfl_xor(v, 4, 64);
            v += __shfl_xor(v, 8, 64);
            if (hl == 0) {
                int row = m0 + wm * 64 + mf * 16 + hi * 4 + rg;
                atomicAdd(&logits[row], v);
            }
        }
    }
}

__global__ __launch_bounds__(128) void reduce_out(const float* __restrict__ logits,
                                                  const int* __restrict__ index,
                                                  const int* __restrict__ cum,
                                                  float* __restrict__ out) {
    int b = blockIdx.x, t = threadIdx.x;
    int idx = index[b];
    int base = cum[b];
    float v = 0.f;
    if (t < 100 && t < idx) v = sigf(logits[base + t]);
    for (int m = 32; m; m >>= 1) v += __shfl_down(v, m, 64);
    __shared__ float s[2];
    if ((t & 63) == 0) s[t >> 6] = v;
    __syncthreads();
    if (t == 0) out[b] = s[0] + s[1];
}

// ---------------- host ----------------

extern "C" void kernel_launch(void* const* d_in, const int* in_sizes, int n_in,
                              void* d_out, int out_size, void* d_ws, size_t ws_size,
                              hipStream_t stream) {
    (void)in_sizes; (void)n_in; (void)out_size; (void)ws_size;
    const float* box = (const float*)d_in[2];
    const float* qf  = (const float*)d_in[3];
    const int* index = (const int*)d_in[5];
    const float* Wih = (const float*)d_in[6];
    const float* Whh = (const float*)d_in[7];
    const float* bih = (const float*)d_in[8];
    const float* bhh = (const float*)d_in[9];
    const float* Ww  = (const float*)d_in[10];
    const float* Wb  = (const float*)d_in[11];
    const float* Wpw = (const float*)d_in[12];
    const float* Wpb = (const float*)d_in[13];
    const float* fw  = (const float*)d_in[14];

    char* p = (char*)d_ws;
    short* Wstk = (short*)p;  p += (size_t)4096 * 1344 * 2;
    short* Wcat = (short*)p;  p += (size_t)1024 * 3072 * 2;
    short* xb   = (short*)p;  p += (size_t)3584 * 320 * 2;
    short* hb0  = (short*)p;  p += (size_t)256 * 1024 * 2;
    short* hb1  = (short*)p;  p += (size_t)256 * 1024 * 2;
    short* xg   = (short*)p;  p += (size_t)3584 * 4096 * 2;
    int*   cum  = (int*)p;    p += 260 * 4;
    int*   ctr  = (int*)p;    p += 1024;
    float* lgt  = (float*)p;  p += (size_t)25600 * 4;
    p = (char*)(((uintptr_t)p + 255) & ~(uintptr_t)255);
    short* Ac   = (short*)p;  p += (size_t)25600 * 3072 * 2;   // ~157 MB

    hipMemsetAsync(ctr, 0, 1024, stream);
    hipMemsetAsync(lgt, 0, (size_t)25600 * 4, stream);

    prep_index<<<1, 256, 0, stream>>>(index, cum);
    prep_wstk<<<(4096 * 1344) / 256, 256, 0, stream>>>(Wih, Whh, bih, bhh, Wstk);
    prep_x<<<(14 * 256 * 320) / 256, 256, 0, stream>>>(qf, xb);
    prep_wcat<<<(1024 * 3072) / 256, 256, 0, stream>>>(Ww, Wpw, Wcat);

    xg_gemm<<<dim3(32, 28), 256, 0, stream>>>(xb, Wstk, xg);
    lstm_persist<<<256, 256, 0, stream>>>(xg, Wstk, hb0, hb1, ctr);
    // final hidden state h_14 in hb0

    compact_a<<<25600, 256, 0, stream>>>(box, hb0, index, cum, Ac);
    mlp_gemm<<<1600, 256, 0, stream>>>(Ac, Wcat, cum + 256, Wb, Wpb, fw, lgt);
    reduce_out<<<256, 128, 0, stream>>>(lgt, index, cum, (float*)d_out);
}

// Round 5
// 410.012 us; speedup vs baseline: 2.4202x; 2.4202x over previous
//
#include <hip/hip_runtime.h>
#include <cstdint>
#include <cstddef>

#define DEVI __device__ __forceinline__

typedef __attribute__((ext_vector_type(8))) short short8;
typedef __attribute__((ext_vector_type(4))) float f32x4;
typedef __attribute__((ext_vector_type(4))) int i32x4;
typedef __bf16 bf16x8 __attribute__((ext_vector_type(8)));

DEVI float sigf(float x) { return 1.0f / (1.0f + __expf(-x)); }
DEVI float tanh_f(float x) { return 2.0f / (1.0f + __expf(-2.0f * x)) - 1.0f; }

DEVI short f2bf(float x) {
    uint32_t u = __builtin_bit_cast(uint32_t, x);
    u += 0x7FFFu + ((u >> 16) & 1u);   // RTNE
    return (short)(u >> 16);
}
DEVI float bf2f(short s) {
    uint32_t u = ((uint32_t)(unsigned short)s) << 16;
    return __builtin_bit_cast(float, u);
}
DEVI uint32_t cvtpk(float lo, float hi) {   // 2x f32 -> packed bf16 (1 VALU op)
    uint32_t r;
    asm("v_cvt_pk_bf16_f32 %0, %1, %2" : "=v"(r) : "v"(lo), "v"(hi));
    return r;
}

DEVI void gload16(const void* g, void* l) {
    __builtin_amdgcn_global_load_lds(
        (const __attribute__((address_space(1))) void*)g,
        (__attribute__((address_space(3))) void*)l, 16, 0, 0);
}

DEVI f32x4 mfma16(short8 a, short8 b, f32x4 c) {
    return __builtin_amdgcn_mfma_f32_16x16x32_bf16(
        __builtin_bit_cast(bf16x8, a), __builtin_bit_cast(bf16x8, b), c, 0, 0, 0);
}

// ---------------- prep kernels ----------------

// Wstk[n'][k], n' = hblk*64 + gate*16 + hl  (orig gate row = gate*1024 + hblk*16 + hl)
// k: [0,300)=W_ih, k==300 -> b_ih+b_hh (paired with constant-1.0 x column),
//    (300,320)=0, [320,1344)=W_hh
__global__ __launch_bounds__(256) void prep_wstk(const float* __restrict__ Wih,
                                                 const float* __restrict__ Whh,
                                                 const float* __restrict__ bih,
                                                 const float* __restrict__ bhh,
                                                 short* __restrict__ Wstk) {
    int idx = blockIdx.x * 256 + threadIdx.x;
    if (idx >= 4096 * 1344) return;
    int n = idx / 1344, k = idx - n * 1344;
    int hblk = n >> 6, gate = (n >> 4) & 3, hl = n & 15;
    int on = gate * 1024 + hblk * 16 + hl;
    float v = 0.f;
    if (k < 300) v = Wih[on * 300 + k];
    else if (k == 300) v = bih[on] + bhh[on];
    else if (k >= 320) v = Whh[on * 1024 + (k - 320)];
    Wstk[idx] = f2bf(v);
}

// x_bf16[t][b][e], e in [0,320): e<300 -> q, e==300 -> 1.0 (bias), else 0.
__global__ __launch_bounds__(256) void prep_x(const float* __restrict__ q,
                                              short* __restrict__ xb) {
    int idx = blockIdx.x * 256 + threadIdx.x;
    if (idx >= 14 * 256 * 320) return;
    int t = idx / (256 * 320);
    int r = idx - t * 256 * 320;
    int b = r / 320, e = r - b * 320;
    float v = (e < 300) ? q[(b * 14 + t) * 300 + e] : (e == 300 ? 1.0f : 0.0f);
    xb[idx] = f2bf(v);
}

// Wcat[n'][k], n' in [0,1024): hg=n'>>5, which=(n'>>4)&1, h=hg*16+(n'&15).
__global__ __launch_bounds__(256) void prep_wcat(const float* __restrict__ Ww,
                                                 const float* __restrict__ Wpw,
                                                 short* __restrict__ Wcat) {
    int idx = blockIdx.x * 256 + threadIdx.x;
    if (idx >= 1024 * 3072) return;
    int n = idx / 3072, k = idx - n * 3072;
    int hg = n >> 5, which = (n >> 4) & 1, hl = n & 15;
    int h = hg * 16 + hl;
    const float* src = which ? Wpw : Ww;
    Wcat[idx] = f2bf(src[h * 3072 + k]);
}

// exclusive prefix sum of index[256] -> cum[0..256]; cum[256]=Mlive.
// Also builds rowmap[dr] = original row, bmap[dr] = sample b, for dr < Mlive,
// plus 128 pad entries (mapped to row 0) so the tail tile reads valid memory.
__global__ __launch_bounds__(256) void prep_index(const int* __restrict__ index,
                                                  int* __restrict__ cum,
                                                  int* __restrict__ rowmap,
                                                  int* __restrict__ bmap) {
    __shared__ int s[256];
    int t = threadIdx.x;
    int myidx = index[t];
    s[t] = myidx;
    __syncthreads();
    for (int off = 1; off < 256; off <<= 1) {
        int v = (t >= off) ? s[t - off] : 0;
        __syncthreads();
        s[t] += v;
        __syncthreads();
    }
    cum[t + 1] = s[t];
    if (t == 0) cum[0] = 0;
    int base = s[t] - myidx;
    for (int j = 0; j < myidx; ++j) {
        rowmap[base + j] = t * 100 + j;
        bmap[base + j] = t;
    }
    int Ml = s[255];
    if (t < 128) { rowmap[Ml + t] = 0; bmap[Ml + t] = 0; }
}

// ---------------- LSTM part 1: x-projection for all timesteps ----------------

// xg[t*256+b][n'] = xb @ Wstk(:, 0:320)^T, bf16 out. M=3584, N=4096, K=320.
__global__ __launch_bounds__(256) void xg_gemm(const short* __restrict__ xb,   // [3584][320]
                                               const short* __restrict__ Wstk, // [4096][1344]
                                               short* __restrict__ xg) {       // [3584][4096]
    __shared__ __attribute__((aligned(16))) short As[128 * 64];
    __shared__ __attribute__((aligned(16))) short Bs[128 * 64];
    const int tid = threadIdx.x, l = tid & 63, w = tid >> 6;
    const int n0 = blockIdx.x * 128;  // 32
    const int m0 = blockIdx.y * 128;  // 28
    const int wm = w >> 1, wn = w & 1;

    const short* asrc[4];
    const short* bsrc[4];
    for (int i = 0; i < 4; i++) {
        int r = w * 32 + i * 8 + (l >> 3);
        int cs = (l & 7) ^ (r & 7);
        asrc[i] = xb + (size_t)(m0 + r) * 320 + cs * 8;
        bsrc[i] = Wstk + (size_t)(n0 + r) * 1344 + cs * 8;
    }

    f32x4 acc[4][4];
    for (int i = 0; i < 4; i++)
        for (int j = 0; j < 4; j++) acc[i][j] = f32x4{0.f, 0.f, 0.f, 0.f};

    for (int kt = 0; kt < 5; ++kt) {
        const int k0 = kt * 64;
        __syncthreads();
        for (int i = 0; i < 4; i++)
            gload16(asrc[i] + k0, &As[(w * 32 + i * 8) * 64]);
        for (int i = 0; i < 4; i++)
            gload16(bsrc[i] + k0, &Bs[(w * 32 + i * 8) * 64]);
        __syncthreads();
        for (int ks = 0; ks < 2; ++ks) {
            short8 a[4], b[4];
            for (int mf = 0; mf < 4; ++mf) {
                int m = wm * 64 + mf * 16 + (l & 15);
                int ca = (ks * 4 + (l >> 4)) ^ (m & 7);
                a[mf] = *(const short8*)&As[m * 64 + ca * 8];
            }
            for (int nf = 0; nf < 4; ++nf) {
                int n = wn * 64 + nf * 16 + (l & 15);
                int cb = (ks * 4 + (l >> 4)) ^ (n & 7);
                b[nf] = *(const short8*)&Bs[n * 64 + cb * 8];
            }
            for (int mf = 0; mf < 4; ++mf)
                for (int nf = 0; nf < 4; ++nf)
                    acc[mf][nf] = mfma16(a[mf], b[nf], acc[mf][nf]);
        }
    }
    const int hl = l & 15, hi = l >> 4;
    for (int mf = 0; mf < 4; ++mf)
        for (int nf = 0; nf < 4; ++nf)
            for (int rg = 0; rg < 4; ++rg) {
                int row = m0 + wm * 64 + mf * 16 + hi * 4 + rg;
                int col = n0 + wn * 64 + nf * 16 + hl;
                xg[(size_t)row * 4096 + col] = f2bf(acc[mf][nf][rg]);
            }
}

// ---------------- LSTM part 2: per-step recurrent GEMM + fused cell ----------------

// gates = h_t @ Whh'^T (+ xg[t]); K=1024 (Wstk cols 320..1344). Tile 32m x 64n',
// 2 waves (128 thr), grid 512 (2 blocks/CU), XCD-pinned n' panels for W L2 reuse.
// kiters=0 for t=0 (h_0 = 0).
__global__ __launch_bounds__(128) void lstm_step(const short* __restrict__ hin,  // [256][1024]
                                                 const short* __restrict__ Wstk, // [4096][1344]
                                                 const short* __restrict__ xg_t, // [256][4096]
                                                 float* __restrict__ c,          // [256][1024]
                                                 short* __restrict__ hout,
                                                 int kiters) {
    __shared__ __attribute__((aligned(16))) short As[32 * 64];
    __shared__ __attribute__((aligned(16))) short Bs[64 * 64];
    const int tid = threadIdx.x, l = tid & 63, w = tid >> 6;
    const int hi = l >> 4, hl = l & 15;
    const int bid = blockIdx.x;             // 512
    const int xcd = bid & 7, ii = bid >> 3;
    const int ny = xcd * 8 + (ii & 7);      // n' panel [0,64)
    const int mx = ii >> 3;                 // m panel [0,8)
    const int m0 = mx * 32, n0g = ny * 64;

    const short* asrc[2];
    const short* bsrc[4];
    for (int i = 0; i < 2; i++) {
        int slot = i * 128 + w * 64 + l;
        int r = slot >> 3, cs = (slot & 7) ^ (r & 7);
        asrc[i] = hin + (size_t)(m0 + r) * 1024 + cs * 8;
    }
    for (int i = 0; i < 4; i++) {
        int slot = i * 128 + w * 64 + l;
        int r = slot >> 3, cs = (slot & 7) ^ (r & 7);
        bsrc[i] = Wstk + (size_t)(n0g + r) * 1344 + 320 + cs * 8;
    }

    f32x4 acc[4];
    for (int i = 0; i < 4; i++) acc[i] = f32x4{0.f, 0.f, 0.f, 0.f};

    for (int kt = 0; kt < kiters; ++kt) {
        const int k0 = kt * 64;
        __syncthreads();
        for (int i = 0; i < 2; i++)
            gload16(asrc[i] + k0, As + (size_t)(i * 128 + w * 64) * 8);
        for (int i = 0; i < 4; i++)
            gload16(bsrc[i] + k0, Bs + (size_t)(i * 128 + w * 64) * 8);
        __syncthreads();
        for (int ks = 0; ks < 2; ++ks) {
            const int mrow = w * 16 + hl;
            const int ca = (ks * 4 + hi) ^ (hl & 7);
            short8 a = *(const short8*)&As[mrow * 64 + ca * 8];
            for (int nf = 0; nf < 4; ++nf) {
                const int nrow = nf * 16 + hl;
                short8 b = *(const short8*)&Bs[nrow * 64 + ca * 8];
                acc[nf] = mfma16(a, b, acc[nf]);
            }
        }
    }

    // epilogue: acc[gate] + xg -> cell update -> h_{t+1}
    const short* xr0 = xg_t + (size_t)(m0 + w * 16 + hi * 4) * 4096 + n0g + hl;
    for (int rg = 0; rg < 4; ++rg) {
        const short* xr = xr0 + (size_t)rg * 4096;
        float ig = acc[0][rg] + bf2f(xr[0]);
        float fg = acc[1][rg] + bf2f(xr[16]);
        float gg = acc[2][rg] + bf2f(xr[32]);
        float og = acc[3][rg] + bf2f(xr[48]);
        size_t off = (size_t)(m0 + w * 16 + hi * 4 + rg) * 1024 + ny * 16 + hl;
        float cn = sigf(fg) * c[off] + sigf(ig) * tanh_f(gg);
        c[off] = cn;
        hout[off] = f2bf(sigf(og) * tanh_f(cn));
    }
}

// ---------------- gated MLP (indirect compacted rows, branch-free) ----------------

// C[dr][1024]: A row dr = box[rowmap[dr]] (f32, reg-staged->bf16) ‖ h[bmap[dr]].
// 128x128 tile, BK=64, 4 waves (2x2). Epilogue fuses tanh*sig*f_w + atomicAdd.
__global__ __launch_bounds__(256) void mlp_gemm(const float* __restrict__ box,  // [25600][2048]
                                                const short* __restrict__ hb,   // [256][1024]
                                                const short* __restrict__ Wcat, // [1024][3072]
                                                const int* __restrict__ mliveptr,
                                                const int* __restrict__ rowmap,
                                                const int* __restrict__ bmap,
                                                const float* __restrict__ Wb,
                                                const float* __restrict__ Wpb,
                                                const float* __restrict__ fw,
                                                float* __restrict__ logits) {
    __shared__ __attribute__((aligned(16))) short As[128 * 64];
    __shared__ __attribute__((aligned(16))) short Bs[128 * 64];
    const int Mlive = *mliveptr;
    const int tid = threadIdx.x, l = tid & 63, w = tid >> 6;
    const int bid = blockIdx.x;              // 1600
    const int xcd = bid & 7, ii = bid >> 3;  // ii in [0,200)
    const int x = ii & 7, q = ii >> 3;       // q in [0,25)
    const int y = q * 8 + xcd;
    const int n0 = x * 128, m0 = y * 128;
    if (m0 >= Mlive) return;
    const int wm = w >> 1, wn = w & 1;

    // box staging: 4 slots/thread, slot -> (row r, chunk cc); indirect row map
    const float* boxp[4];
    short* awr[4];
    for (int i = 0; i < 4; i++) {
        int slot = tid + i * 256;
        int r = slot >> 3, cc = slot & 7;
        boxp[i] = box + (size_t)rowmap[m0 + r] * 2048 + cc * 8;
        awr[i] = &As[r * 64 + ((cc ^ (r & 7)) * 8)];
    }
    // h staging (gload16) + B staging
    const short* hsrc[4];
    const short* bsrc[4];
    for (int i = 0; i < 4; i++) {
        int r = w * 32 + i * 8 + (l >> 3);
        int cs = (l & 7) ^ (r & 7);
        hsrc[i] = hb + (size_t)bmap[m0 + r] * 1024 + cs * 8;
        bsrc[i] = Wcat + (size_t)(n0 + r) * 3072 + cs * 8;
    }

    f32x4 acc[4][4];
    for (int i = 0; i < 4; i++)
        for (int j = 0; j < 4; j++) acc[i][j] = f32x4{0.f, 0.f, 0.f, 0.f};

    for (int kt = 0; kt < 48; ++kt) {
        const int k0 = kt * 64;
        __syncthreads();
        if (kt < 32) {
            for (int i = 0; i < 4; i++) {
                float4 v0 = *(const float4*)(boxp[i] + k0);
                float4 v1 = *(const float4*)(boxp[i] + k0 + 4);
                i32x4 d;
                d[0] = (int)cvtpk(v0.x, v0.y);
                d[1] = (int)cvtpk(v0.z, v0.w);
                d[2] = (int)cvtpk(v1.x, v1.y);
                d[3] = (int)cvtpk(v1.z, v1.w);
                *(i32x4*)awr[i] = d;
            }
        } else {
            const int kq = k0 - 2048;
            for (int i = 0; i < 4; i++)
                gload16(hsrc[i] + kq, &As[(w * 32 + i * 8) * 64]);
        }
        for (int i = 0; i < 4; i++)
            gload16(bsrc[i] + k0, &Bs[(w * 32 + i * 8) * 64]);
        __syncthreads();
        for (int ks = 0; ks < 2; ++ks) {
            short8 a[4], b[4];
            for (int mf = 0; mf < 4; ++mf) {
                int m = wm * 64 + mf * 16 + (l & 15);
                int ca = (ks * 4 + (l >> 4)) ^ (m & 7);
                a[mf] = *(const short8*)&As[m * 64 + ca * 8];
            }
            for (int nf = 0; nf < 4; ++nf) {
                int n = wn * 64 + nf * 16 + (l & 15);
                int cb = (ks * 4 + (l >> 4)) ^ (n & 7);
                b[nf] = *(const short8*)&Bs[n * 64 + cb * 8];
            }
            for (int mf = 0; mf < 4; ++mf)
                for (int nf = 0; nf < 4; ++nf)
                    acc[mf][nf] = mfma16(a[mf], b[nf], acc[mf][nf]);
        }
    }

    const int hl = l & 15, hi = l >> 4;
    for (int mf = 0; mf < 4; ++mf) {
        float part[4] = {0.f, 0.f, 0.f, 0.f};
        for (int p = 0; p < 2; ++p) {
            int ntg = (n0 + wn * 64) / 16 + 2 * p;
            int hg = ntg >> 1;
            int h = hg * 16 + hl;
            float fwv = fw[h], wbv = Wb[h], wpbv = Wpb[h];
            for (int rg = 0; rg < 4; ++rg) {
                float y2 = tanh_f(acc[mf][2 * p][rg] + wbv);
                float g2 = sigf(acc[mf][2 * p + 1][rg] + wpbv);
                part[rg] += y2 * g2 * fwv;
            }
        }
        for (int rg = 0; rg < 4; ++rg) {
            float v = part[rg];
            v += __shfl_xor(v, 1, 64);
            v += __shfl_xor(v, 2, 64);
            v += __shfl_xor(v, 4, 64);
            v += __shfl_xor(v, 8, 64);
            if (hl == 0) {
                int row = m0 + wm * 64 + mf * 16 + hi * 4 + rg;
                atomicAdd(&logits[row], v);
            }
        }
    }
}

__global__ __launch_bounds__(128) void reduce_out(const float* __restrict__ logits,
                                                  const int* __restrict__ index,
                                                  const int* __restrict__ cum,
                                                  float* __restrict__ out) {
    int b = blockIdx.x, t = threadIdx.x;
    int idx = index[b];
    int base = cum[b];
    float v = 0.f;
    if (t < 100 && t < idx) v = sigf(logits[base + t]);
    for (int m = 32; m; m >>= 1) v += __shfl_down(v, m, 64);
    __shared__ float s[2];
    if ((t & 63) == 0) s[t >> 6] = v;
    __syncthreads();
    if (t == 0) out[b] = s[0] + s[1];
}

// ---------------- host ----------------

extern "C" void kernel_launch(void* const* d_in, const int* in_sizes, int n_in,
                              void* d_out, int out_size, void* d_ws, size_t ws_size,
                              hipStream_t stream) {
    (void)in_sizes; (void)n_in; (void)out_size; (void)ws_size;
    const float* box = (const float*)d_in[2];
    const float* qf  = (const float*)d_in[3];
    const int* index = (const int*)d_in[5];
    const float* Wih = (const float*)d_in[6];
    const float* Whh = (const float*)d_in[7];
    const float* bih = (const float*)d_in[8];
    const float* bhh = (const float*)d_in[9];
    const float* Ww  = (const float*)d_in[10];
    const float* Wb  = (const float*)d_in[11];
    const float* Wpw = (const float*)d_in[12];
    const float* Wpb = (const float*)d_in[13];
    const float* fw  = (const float*)d_in[14];

    char* p = (char*)d_ws;
    short* Wstk = (short*)p;  p += (size_t)4096 * 1344 * 2;
    short* Wcat = (short*)p;  p += (size_t)1024 * 3072 * 2;
    short* xb   = (short*)p;  p += (size_t)3584 * 320 * 2;
    short* hb0  = (short*)p;  p += (size_t)256 * 1024 * 2;
    short* hb1  = (short*)p;  p += (size_t)256 * 1024 * 2;
    short* xg   = (short*)p;  p += (size_t)3584 * 4096 * 2;
    float* c    = (float*)p;  p += (size_t)256 * 1024 * 4;
    int*   cum  = (int*)p;    p += 260 * 4;
    int*   rowmap = (int*)p;  p += (size_t)(25600 + 128) * 4;
    int*   bmap = (int*)p;    p += (size_t)(25600 + 128) * 4;
    float* lgt  = (float*)p;  p += (size_t)25600 * 4;

    hipMemsetAsync(hb0, 0, (size_t)256 * 1024 * 2, stream);
    hipMemsetAsync(c, 0, (size_t)256 * 1024 * 4, stream);
    hipMemsetAsync(lgt, 0, (size_t)25600 * 4, stream);

    prep_index<<<1, 256, 0, stream>>>(index, cum, rowmap, bmap);
    prep_wstk<<<(4096 * 1344) / 256, 256, 0, stream>>>(Wih, Whh, bih, bhh, Wstk);
    prep_x<<<(14 * 256 * 320) / 256, 256, 0, stream>>>(qf, xb);
    prep_wcat<<<(1024 * 3072) / 256, 256, 0, stream>>>(Ww, Wpw, Wcat);

    xg_gemm<<<dim3(32, 28), 256, 0, stream>>>(xb, Wstk, xg);

    short* hbuf[2] = {hb0, hb1};
    for (int t = 0; t < 14; ++t) {
        lstm_step<<<512, 128, 0, stream>>>(
            hbuf[t & 1], Wstk, xg + (size_t)t * 256 * 4096, c,
            hbuf[(t & 1) ^ 1], t == 0 ? 0 : 16);
    }
    // final hidden state h_14 in hb0

    mlp_gemm<<<1600, 256, 0, stream>>>(box, hb0, Wcat, cum + 256, rowmap, bmap,
                                       Wb, Wpb, fw, lgt);
    reduce_out<<<256, 128, 0, stream>>>(lgt, index, cum, (float*)d_out);
}

// Round 6
// 346.727 us; speedup vs baseline: 2.8620x; 1.1825x over previous
//
#include <hip/hip_runtime.h>
#include <cstdint>
#include <cstddef>

#define DEVI __device__ __forceinline__

typedef __attribute__((ext_vector_type(8))) short short8;
typedef __attribute__((ext_vector_type(4))) float f32x4;
typedef __attribute__((ext_vector_type(4))) int i32x4;
typedef __bf16 bf16x8 __attribute__((ext_vector_type(8)));

DEVI float sigf(float x) { return 1.0f / (1.0f + __expf(-x)); }
DEVI float tanh_f(float x) { return 2.0f / (1.0f + __expf(-2.0f * x)) - 1.0f; }

DEVI short f2bf(float x) {
    uint32_t u = __builtin_bit_cast(uint32_t, x);
    u += 0x7FFFu + ((u >> 16) & 1u);   // RTNE
    return (short)(u >> 16);
}
DEVI float bf2f(short s) {
    uint32_t u = ((uint32_t)(unsigned short)s) << 16;
    return __builtin_bit_cast(float, u);
}
DEVI uint32_t cvtpk(float lo, float hi) {   // 2x f32 -> packed bf16 (1 VALU op)
    uint32_t r;
    asm("v_cvt_pk_bf16_f32 %0, %1, %2" : "=v"(r) : "v"(lo), "v"(hi));
    return r;
}

DEVI void gload16(const void* g, void* l) {
    __builtin_amdgcn_global_load_lds(
        (const __attribute__((address_space(1))) void*)g,
        (__attribute__((address_space(3))) void*)l, 16, 0, 0);
}

DEVI f32x4 mfma16(short8 a, short8 b, f32x4 c) {
    return __builtin_amdgcn_mfma_f32_16x16x32_bf16(
        __builtin_bit_cast(bf16x8, a), __builtin_bit_cast(bf16x8, b), c, 0, 0, 0);
}

// ---------------- prep kernels ----------------

// Wstk[n'][k], n' = hblk*64 + gate*16 + hl  (orig gate row = gate*1024 + hblk*16 + hl)
// k: [0,300)=W_ih, k==300 -> b_ih+b_hh (paired with constant-1.0 x column),
//    (300,320)=0, [320,1344)=W_hh
__global__ __launch_bounds__(256) void prep_wstk(const float* __restrict__ Wih,
                                                 const float* __restrict__ Whh,
                                                 const float* __restrict__ bih,
                                                 const float* __restrict__ bhh,
                                                 short* __restrict__ Wstk) {
    int idx = blockIdx.x * 256 + threadIdx.x;
    if (idx >= 4096 * 1344) return;
    int n = idx / 1344, k = idx - n * 1344;
    int hblk = n >> 6, gate = (n >> 4) & 3, hl = n & 15;
    int on = gate * 1024 + hblk * 16 + hl;
    float v = 0.f;
    if (k < 300) v = Wih[on * 300 + k];
    else if (k == 300) v = bih[on] + bhh[on];
    else if (k >= 320) v = Whh[on * 1024 + (k - 320)];
    Wstk[idx] = f2bf(v);
}

// x_bf16[t][b][e], e in [0,320): e<300 -> q, e==300 -> 1.0 (bias), else 0.
__global__ __launch_bounds__(256) void prep_x(const float* __restrict__ q,
                                              short* __restrict__ xb) {
    int idx = blockIdx.x * 256 + threadIdx.x;
    if (idx >= 14 * 256 * 320) return;
    int t = idx / (256 * 320);
    int r = idx - t * 256 * 320;
    int b = r / 320, e = r - b * 320;
    float v = (e < 300) ? q[(b * 14 + t) * 300 + e] : (e == 300 ? 1.0f : 0.0f);
    xb[idx] = f2bf(v);
}

// Wcat[n'][k], n' in [0,1024): hg=n'>>5, which=(n'>>4)&1, h=hg*16+(n'&15).
__global__ __launch_bounds__(256) void prep_wcat(const float* __restrict__ Ww,
                                                 const float* __restrict__ Wpw,
                                                 short* __restrict__ Wcat) {
    int idx = blockIdx.x * 256 + threadIdx.x;
    if (idx >= 1024 * 3072) return;
    int n = idx / 3072, k = idx - n * 3072;
    int hg = n >> 5, which = (n >> 4) & 1, hl = n & 15;
    int h = hg * 16 + hl;
    const float* src = which ? Wpw : Ww;
    Wcat[idx] = f2bf(src[h * 3072 + k]);
}

// exclusive prefix sum of index[256] -> cum[0..256]; cum[256]=Mlive.
// Also builds rowmap[dr]/bmap[dr] for dr < Mlive + 128 pad entries -> row 0.
__global__ __launch_bounds__(256) void prep_index(const int* __restrict__ index,
                                                  int* __restrict__ cum,
                                                  int* __restrict__ rowmap,
                                                  int* __restrict__ bmap) {
    __shared__ int s[256];
    int t = threadIdx.x;
    int myidx = index[t];
    s[t] = myidx;
    __syncthreads();
    for (int off = 1; off < 256; off <<= 1) {
        int v = (t >= off) ? s[t - off] : 0;
        __syncthreads();
        s[t] += v;
        __syncthreads();
    }
    cum[t + 1] = s[t];
    if (t == 0) cum[0] = 0;
    int base = s[t] - myidx;
    for (int j = 0; j < myidx; ++j) {
        rowmap[base + j] = t * 100 + j;
        bmap[base + j] = t;
    }
    int Ml = s[255];
    if (t < 128) { rowmap[Ml + t] = 0; bmap[Ml + t] = 0; }
}

// ---------------- LSTM part 1: x-projection for all timesteps ----------------

// xg[t*256+b][n'] = xb @ Wstk(:, 0:320)^T, bf16 out. M=3584, N=4096, K=320.
__global__ __launch_bounds__(256) void xg_gemm(const short* __restrict__ xb,   // [3584][320]
                                               const short* __restrict__ Wstk, // [4096][1344]
                                               short* __restrict__ xg) {       // [3584][4096]
    __shared__ __attribute__((aligned(16))) short As[128 * 64];
    __shared__ __attribute__((aligned(16))) short Bs[128 * 64];
    const int tid = threadIdx.x, l = tid & 63, w = tid >> 6;
    const int n0 = blockIdx.x * 128;  // 32
    const int m0 = blockIdx.y * 128;  // 28
    const int wm = w >> 1, wn = w & 1;

    const short* asrc[4];
    const short* bsrc[4];
    for (int i = 0; i < 4; i++) {
        int r = w * 32 + i * 8 + (l >> 3);
        int cs = (l & 7) ^ (r & 7);
        asrc[i] = xb + (size_t)(m0 + r) * 320 + cs * 8;
        bsrc[i] = Wstk + (size_t)(n0 + r) * 1344 + cs * 8;
    }

    f32x4 acc[4][4];
    for (int i = 0; i < 4; i++)
        for (int j = 0; j < 4; j++) acc[i][j] = f32x4{0.f, 0.f, 0.f, 0.f};

    for (int kt = 0; kt < 5; ++kt) {
        const int k0 = kt * 64;
        __syncthreads();
        for (int i = 0; i < 4; i++)
            gload16(asrc[i] + k0, &As[(w * 32 + i * 8) * 64]);
        for (int i = 0; i < 4; i++)
            gload16(bsrc[i] + k0, &Bs[(w * 32 + i * 8) * 64]);
        __syncthreads();
        for (int ks = 0; ks < 2; ++ks) {
            short8 a[4], b[4];
            for (int mf = 0; mf < 4; ++mf) {
                int m = wm * 64 + mf * 16 + (l & 15);
                int ca = (ks * 4 + (l >> 4)) ^ (m & 7);
                a[mf] = *(const short8*)&As[m * 64 + ca * 8];
            }
            for (int nf = 0; nf < 4; ++nf) {
                int n = wn * 64 + nf * 16 + (l & 15);
                int cb = (ks * 4 + (l >> 4)) ^ (n & 7);
                b[nf] = *(const short8*)&Bs[n * 64 + cb * 8];
            }
            for (int mf = 0; mf < 4; ++mf)
                for (int nf = 0; nf < 4; ++nf)
                    acc[mf][nf] = mfma16(a[mf], b[nf], acc[mf][nf]);
        }
    }
    const int hl = l & 15, hi = l >> 4;
    for (int mf = 0; mf < 4; ++mf)
        for (int nf = 0; nf < 4; ++nf)
            for (int rg = 0; rg < 4; ++rg) {
                int row = m0 + wm * 64 + mf * 16 + hi * 4 + rg;
                int col = n0 + wn * 64 + nf * 16 + hl;
                xg[(size_t)row * 4096 + col] = f2bf(acc[mf][nf][rg]);
            }
}

// ---------------- LSTM part 2: per-step recurrent GEMM, dbuf pipelined ----------------

// gates = h_t @ Whh'^T (+ xg[t]); K=1024, BK=128 (8 kt), double-buffered LDS,
// counted vmcnt so prefetch stays in flight across barriers. Tile 32m x 64n',
// 2 waves, grid 512 (2 blocks/CU), XCD-pinned n' panels.
__global__ __launch_bounds__(128) void lstm_step(const short* __restrict__ hin,  // [256][1024]
                                                 const short* __restrict__ Wstk, // [4096][1344]
                                                 const short* __restrict__ xg_t, // [256][4096]
                                                 float* __restrict__ c,          // [256][1024]
                                                 short* __restrict__ hout,
                                                 int dogemm) {
    __shared__ __attribute__((aligned(16))) short As[2][32 * 128];
    __shared__ __attribute__((aligned(16))) short Bs[2][64 * 128];
    const int tid = threadIdx.x, l = tid & 63, w = tid >> 6;
    const int hi = l >> 4, hl = l & 15;
    const int bid = blockIdx.x;             // 512
    const int xcd = bid & 7, ii = bid >> 3;
    const int ny = xcd * 8 + (ii & 7);      // n' panel [0,64)
    const int mx = ii >> 3;                 // m panel [0,8)
    const int m0 = mx * 32, n0g = ny * 64;

    f32x4 acc[4];
    for (int i = 0; i < 4; i++) acc[i] = f32x4{0.f, 0.f, 0.f, 0.f};

    if (dogemm) {
        const short* asrc[4];
        const short* bsrc[8];
        for (int i = 0; i < 4; i++) {
            int s = i * 128 + tid;
            int r = s >> 4, cs = s & 15;
            asrc[i] = hin + (size_t)(m0 + r) * 1024 + ((cs ^ (r & 15)) * 8);
        }
        for (int i = 0; i < 8; i++) {
            int s = i * 128 + tid;
            int r = s >> 4, cs = s & 15;
            bsrc[i] = Wstk + (size_t)(n0g + r) * 1344 + 320 + ((cs ^ (r & 15)) * 8);
        }
        // prologue: stage kt=0 into buf 0
        for (int i = 0; i < 4; i++) gload16(asrc[i], &As[0][(i * 128 + tid) * 8]);
        for (int i = 0; i < 8; i++) gload16(bsrc[i], &Bs[0][(i * 128 + tid) * 8]);

        for (int kt = 0; kt < 8; ++kt) {
            const int cur = kt & 1;
            if (kt < 7) {
                const int k0 = (kt + 1) * 128;
                for (int i = 0; i < 4; i++)
                    gload16(asrc[i] + k0, &As[cur ^ 1][(i * 128 + tid) * 8]);
                for (int i = 0; i < 8; i++)
                    gload16(bsrc[i] + k0, &Bs[cur ^ 1][(i * 128 + tid) * 8]);
                asm volatile("s_waitcnt vmcnt(12)" ::: "memory");
            } else {
                asm volatile("s_waitcnt vmcnt(0)" ::: "memory");
            }
            __builtin_amdgcn_sched_barrier(0);
            __builtin_amdgcn_s_barrier();
            __builtin_amdgcn_sched_barrier(0);
#pragma unroll
            for (int ks = 0; ks < 4; ++ks) {
                const int mrow = w * 16 + hl;
                const int ca = (ks * 4 + hi) ^ hl;
                short8 a = *(const short8*)&As[cur][mrow * 128 + ca * 8];
#pragma unroll
                for (int nf = 0; nf < 4; ++nf) {
                    const int nrow = nf * 16 + hl;
                    short8 b = *(const short8*)&Bs[cur][nrow * 128 + ca * 8];
                    acc[nf] = mfma16(a, b, acc[nf]);
                }
            }
            __builtin_amdgcn_sched_barrier(0);
            asm volatile("s_waitcnt lgkmcnt(0)" ::: "memory");
            __builtin_amdgcn_s_barrier();
            __builtin_amdgcn_sched_barrier(0);
        }
    }

    // epilogue: acc[gate] + xg -> cell update -> h_{t+1}
    const short* xr0 = xg_t + (size_t)(m0 + w * 16 + hi * 4) * 4096 + n0g + hl;
    for (int rg = 0; rg < 4; ++rg) {
        const short* xr = xr0 + (size_t)rg * 4096;
        float ig = acc[0][rg] + bf2f(xr[0]);
        float fg = acc[1][rg] + bf2f(xr[16]);
        float gg = acc[2][rg] + bf2f(xr[32]);
        float og = acc[3][rg] + bf2f(xr[48]);
        size_t off = (size_t)(m0 + w * 16 + hi * 4 + rg) * 1024 + ny * 16 + hl;
        float cn = sigf(fg) * c[off] + sigf(ig) * tanh_f(gg);
        c[off] = cn;
        hout[off] = f2bf(sigf(og) * tanh_f(cn));
    }
}

// ---------------- gated MLP (indirect rows, reg-prefetched box staging) ----------------

// C[dr][1024]: A row dr = box[rowmap[dr]] (f32 -> bf16 via cvt_pk) ‖ h[bmap[dr]].
// 128x128 tile, BK=64, 4 waves (2x2). Box loads for kt+1 prefetched into regs
// during kt's compute; counted vmcnt(8) keeps them in flight across the barrier.
__global__ __launch_bounds__(256) void mlp_gemm(const float* __restrict__ box,  // [25600][2048]
                                                const short* __restrict__ hb,   // [256][1024]
                                                const short* __restrict__ Wcat, // [1024][3072]
                                                const int* __restrict__ mliveptr,
                                                const int* __restrict__ rowmap,
                                                const int* __restrict__ bmap,
                                                const float* __restrict__ Wb,
                                                const float* __restrict__ Wpb,
                                                const float* __restrict__ fw,
                                                float* __restrict__ logits) {
    __shared__ __attribute__((aligned(16))) short As[128 * 64];
    __shared__ __attribute__((aligned(16))) short Bs[128 * 64];
    const int Mlive = *mliveptr;
    const int tid = threadIdx.x, l = tid & 63, w = tid >> 6;
    const int bid = blockIdx.x;              // 1600
    const int xcd = bid & 7, ii = bid >> 3;  // ii in [0,200)
    const int x = ii & 7, q = ii >> 3;       // q in [0,25)
    const int y = q * 8 + xcd;
    const int n0 = x * 128, m0 = y * 128;
    if (m0 >= Mlive) return;
    const int wm = w >> 1, wn = w & 1;

    const float* boxp[4];
    short* awr[4];
    for (int i = 0; i < 4; i++) {
        int slot = tid + i * 256;
        int r = slot >> 3, cc = slot & 7;
        boxp[i] = box + (size_t)rowmap[m0 + r] * 2048 + cc * 8;
        awr[i] = &As[r * 64 + ((cc ^ (r & 7)) * 8)];
    }
    const short* hsrc[4];
    const short* bsrc[4];
    for (int i = 0; i < 4; i++) {
        int r = w * 32 + i * 8 + (l >> 3);
        int cs = (l & 7) ^ (r & 7);
        hsrc[i] = hb + (size_t)bmap[m0 + r] * 1024 + cs * 8;
        bsrc[i] = Wcat + (size_t)(n0 + r) * 3072 + cs * 8;
    }

    f32x4 acc[4][4];
    for (int i = 0; i < 4; i++)
        for (int j = 0; j < 4; j++) acc[i][j] = f32x4{0.f, 0.f, 0.f, 0.f};

    // prologue: prefetch kt=0 box rows into regs
    float4 pva[4], pvb[4];
    for (int i = 0; i < 4; i++) {
        pva[i] = *(const float4*)(boxp[i]);
        pvb[i] = *(const float4*)(boxp[i] + 4);
    }

    for (int kt = 0; kt < 48; ++kt) {
        const int k0 = kt * 64;
        // top barrier: all waves done reading As/Bs (per-wave reads complete
        // before their MFMAs issue). Raw barrier: pv prefetch stays in flight.
        __builtin_amdgcn_sched_barrier(0);
        __builtin_amdgcn_s_barrier();
        __builtin_amdgcn_sched_barrier(0);
        if (kt < 32) {
            for (int i = 0; i < 4; i++) {
                i32x4 d;
                d[0] = (int)cvtpk(pva[i].x, pva[i].y);
                d[1] = (int)cvtpk(pva[i].z, pva[i].w);
                d[2] = (int)cvtpk(pvb[i].x, pvb[i].y);
                d[3] = (int)cvtpk(pvb[i].z, pvb[i].w);
                *(i32x4*)awr[i] = d;
            }
        } else {
            const int kq = k0 - 2048;
            for (int i = 0; i < 4; i++)
                gload16(hsrc[i] + kq, &As[(w * 32 + i * 8) * 64]);
        }
        for (int i = 0; i < 4; i++)
            gload16(bsrc[i] + k0, &Bs[(w * 32 + i * 8) * 64]);
        if (kt + 1 < 32) {
            const int k1 = (kt + 1) * 64;
            for (int i = 0; i < 4; i++) {
                pva[i] = *(const float4*)(boxp[i] + k1);
                pvb[i] = *(const float4*)(boxp[i] + k1 + 4);
            }
            asm volatile("s_waitcnt vmcnt(8) lgkmcnt(0)" ::: "memory");
        } else {
            asm volatile("s_waitcnt vmcnt(0) lgkmcnt(0)" ::: "memory");
        }
        __builtin_amdgcn_sched_barrier(0);
        __builtin_amdgcn_s_barrier();
        __builtin_amdgcn_sched_barrier(0);
        for (int ks = 0; ks < 2; ++ks) {
            short8 a[4], b[4];
            for (int mf = 0; mf < 4; ++mf) {
                int m = wm * 64 + mf * 16 + (l & 15);
                int ca = (ks * 4 + (l >> 4)) ^ (m & 7);
                a[mf] = *(const short8*)&As[m * 64 + ca * 8];
            }
            for (int nf = 0; nf < 4; ++nf) {
                int n = wn * 64 + nf * 16 + (l & 15);
                int cb = (ks * 4 + (l >> 4)) ^ (n & 7);
                b[nf] = *(const short8*)&Bs[n * 64 + cb * 8];
            }
            for (int mf = 0; mf < 4; ++mf)
                for (int nf = 0; nf < 4; ++nf)
                    acc[mf][nf] = mfma16(a[mf], b[nf], acc[mf][nf]);
        }
    }

    const int hl = l & 15, hi = l >> 4;
    for (int mf = 0; mf < 4; ++mf) {
        float part[4] = {0.f, 0.f, 0.f, 0.f};
        for (int p = 0; p < 2; ++p) {
            int ntg = (n0 + wn * 64) / 16 + 2 * p;
            int hg = ntg >> 1;
            int h = hg * 16 + hl;
            float fwv = fw[h], wbv = Wb[h], wpbv = Wpb[h];
            for (int rg = 0; rg < 4; ++rg) {
                float y2 = tanh_f(acc[mf][2 * p][rg] + wbv);
                float g2 = sigf(acc[mf][2 * p + 1][rg] + wpbv);
                part[rg] += y2 * g2 * fwv;
            }
        }
        for (int rg = 0; rg < 4; ++rg) {
            float v = part[rg];
            v += __shfl_xor(v, 1, 64);
            v += __shfl_xor(v, 2, 64);
            v += __shfl_xor(v, 4, 64);
            v += __shfl_xor(v, 8, 64);
            if (hl == 0) {
                int row = m0 + wm * 64 + mf * 16 + hi * 4 + rg;
                atomicAdd(&logits[row], v);
            }
        }
    }
}

__global__ __launch_bounds__(128) void reduce_out(const float* __restrict__ logits,
                                                  const int* __restrict__ index,
                                                  const int* __restrict__ cum,
                                                  float* __restrict__ out) {
    int b = blockIdx.x, t = threadIdx.x;
    int idx = index[b];
    int base = cum[b];
    float v = 0.f;
    if (t < 100 && t < idx) v = sigf(logits[base + t]);
    for (int m = 32; m; m >>= 1) v += __shfl_down(v, m, 64);
    __shared__ float s[2];
    if ((t & 63) == 0) s[t >> 6] = v;
    __syncthreads();
    if (t == 0) out[b] = s[0] + s[1];
}

// ---------------- host ----------------

extern "C" void kernel_launch(void* const* d_in, const int* in_sizes, int n_in,
                              void* d_out, int out_size, void* d_ws, size_t ws_size,
                              hipStream_t stream) {
    (void)in_sizes; (void)n_in; (void)out_size; (void)ws_size;
    const float* box = (const float*)d_in[2];
    const float* qf  = (const float*)d_in[3];
    const int* index = (const int*)d_in[5];
    const float* Wih = (const float*)d_in[6];
    const float* Whh = (const float*)d_in[7];
    const float* bih = (const float*)d_in[8];
    const float* bhh = (const float*)d_in[9];
    const float* Ww  = (const float*)d_in[10];
    const float* Wb  = (const float*)d_in[11];
    const float* Wpw = (const float*)d_in[12];
    const float* Wpb = (const float*)d_in[13];
    const float* fw  = (const float*)d_in[14];

    char* p = (char*)d_ws;
    short* Wstk = (short*)p;  p += (size_t)4096 * 1344 * 2;
    short* Wcat = (short*)p;  p += (size_t)1024 * 3072 * 2;
    short* xb   = (short*)p;  p += (size_t)3584 * 320 * 2;
    short* hb0  = (short*)p;  p += (size_t)256 * 1024 * 2;
    short* hb1  = (short*)p;  p += (size_t)256 * 1024 * 2;
    short* xg   = (short*)p;  p += (size_t)3584 * 4096 * 2;
    float* c    = (float*)p;  p += (size_t)256 * 1024 * 4;
    int*   cum  = (int*)p;    p += 260 * 4;
    int*   rowmap = (int*)p;  p += (size_t)(25600 + 128) * 4;
    int*   bmap = (int*)p;    p += (size_t)(25600 + 128) * 4;
    float* lgt  = (float*)p;  p += (size_t)25600 * 4;

    hipMemsetAsync(hb0, 0, (size_t)256 * 1024 * 2, stream);
    hipMemsetAsync(c, 0, (size_t)256 * 1024 * 4, stream);
    hipMemsetAsync(lgt, 0, (size_t)25600 * 4, stream);

    prep_index<<<1, 256, 0, stream>>>(index, cum, rowmap, bmap);
    prep_wstk<<<(4096 * 1344) / 256, 256, 0, stream>>>(Wih, Whh, bih, bhh, Wstk);
    prep_x<<<(14 * 256 * 320) / 256, 256, 0, stream>>>(qf, xb);
    prep_wcat<<<(1024 * 3072) / 256, 256, 0, stream>>>(Ww, Wpw, Wcat);

    xg_gemm<<<dim3(32, 28), 256, 0, stream>>>(xb, Wstk, xg);

    short* hbuf[2] = {hb0, hb1};
    for (int t = 0; t < 14; ++t) {
        lstm_step<<<512, 128, 0, stream>>>(
            hbuf[t & 1], Wstk, xg + (size_t)t * 256 * 4096, c,
            hbuf[(t & 1) ^ 1], t == 0 ? 0 : 1);
    }
    // final hidden state h_14 in hb0

    mlp_gemm<<<1600, 256, 0, stream>>>(box, hb0, Wcat, cum + 256, rowmap, bmap,
                                       Wb, Wpb, fw, lgt);
    reduce_out<<<256, 128, 0, stream>>>(lgt, index, cum, (float*)d_out);
}